// Round 17
// baseline (227.395 us; speedup 1.0000x reference)
//
#include <hip/hip_runtime.h>
#include <hip/hip_fp16.h>

#define NPOS   4096
#define CDIM   512
#define CQK    64
#define NBATCH 4
#define L2E 1.44269504088896f

typedef _Float16 f16x8 __attribute__((ext_vector_type(8)));
typedef _Float16 f16x4 __attribute__((ext_vector_type(4)));
typedef float    f32x4 __attribute__((ext_vector_type(4)));

// LDS-only drain barrier: keeps global-load (vmcnt) prefetches in flight across
// the barrier (T4). All cross-wave traffic here is LDS, so lgkmcnt(0) suffices.
#define LDS_BARRIER() asm volatile("s_waitcnt lgkmcnt(0)\ns_barrier" ::: "memory")

// ---------------- x convert+transpose: x[b,c,n] f32 -> Xt[b,n,c] f16 ----------------
__global__ __launch_bounds__(256) void x_cvt_kernel(
    const float* __restrict__ x, _Float16* __restrict__ Xt)
{
    __shared__ _Float16 tile[64][66];
    const int b  = blockIdx.z;
    const int c0 = blockIdx.y * 64;
    const int n0 = blockIdx.x * 64;
    const int tid = threadIdx.x;

    const int rr = tid >> 4;
    const int n4 = (tid & 15) * 4;
#pragma unroll
    for (int i = 0; i < 4; ++i) {
        const int c = i * 16 + rr;
        const float4 v = *reinterpret_cast<const float4*>(
            x + (size_t)(b * CDIM + c0 + c) * NPOS + n0 + n4);
        tile[c][n4 + 0] = (_Float16)v.x;
        tile[c][n4 + 1] = (_Float16)v.y;
        tile[c][n4 + 2] = (_Float16)v.z;
        tile[c][n4 + 3] = (_Float16)v.w;
    }
    __syncthreads();

    const int col = tid & 63;
    const int r4  = tid >> 6;
#pragma unroll
    for (int i = 0; i < 16; ++i) {
        const int n = i * 4 + r4;
        Xt[((size_t)b * NPOS + n0 + n) * CDIM + c0 + col] = tile[col][n];
    }
}

// ---------------- weight convert ----------------
__global__ __launch_bounds__(256) void w_cvt_kernel(
    const float* __restrict__ wq, const float* __restrict__ bq,
    const float* __restrict__ wk, const float* __restrict__ bk,
    const float* __restrict__ wv, const float* __restrict__ bv,
    _Float16* __restrict__ Wh, float* __restrict__ biasc)
{
    const int gid = blockIdx.x * 256 + threadIdx.x;
    const int idx = gid * 4;
    const float* src;
    if (idx < 64 * 512)       src = wq + idx;
    else if (idx < 128 * 512) src = wk + (idx - 64 * 512);
    else                      src = wv + (idx - 128 * 512);
    const float4 v = *reinterpret_cast<const float4*>(src);
    f16x4 h;
    h[0] = (_Float16)v.x; h[1] = (_Float16)v.y;
    h[2] = (_Float16)v.z; h[3] = (_Float16)v.w;
    *reinterpret_cast<f16x4*>(Wh + idx) = h;
    if (gid < 640) {
        float bb;
        if (gid < 64)       bb = bq[gid];
        else if (gid < 128) bb = bk[gid - 64];
        else                bb = bv[gid - 128];
        biasc[gid] = bb;
    }
}

// ---------------- fused QKV projection GEMM: 128x128 tile, LDS double-buffered ----------------
// (R13 structure — measured best; unchanged.)
__global__ __launch_bounds__(256) void proj_gemm_kernel(
    const _Float16* __restrict__ Wh, const float* __restrict__ biasc,
    const _Float16* __restrict__ Xt,
    _Float16* __restrict__ Qp, _Float16* __restrict__ Kp, _Float16* __restrict__ Vp)
{
    __shared__ __align__(16) _Float16 As[2][128 * 32];
    __shared__ __align__(16) _Float16 Bs[2][128 * 32];

    const int tid  = threadIdx.x;
    const int lane = tid & 63;
    const int w    = tid >> 6;       // 0..3
    const int wr   = w >> 1;         // m-half
    const int wc   = w & 1;          // n-half
    const int g    = lane >> 4;
    const int lr   = lane & 15;

    const int b  = blockIdx.z;
    const int m0 = blockIdx.y * 128;
    const int n0 = blockIdx.x * 128;

    const _Float16* xb = Xt + (size_t)b * NPOS * CDIM;

    const int srow = tid >> 2;
    const int schk = (tid & 3) * 8;

    f16x8 sA[2], sB[2];
    auto gload = [&](int kk) {
#pragma unroll
        for (int rnd = 0; rnd < 2; ++rnd) {
            const int row = srow + rnd * 64;
            sA[rnd] = *reinterpret_cast<const f16x8*>(
                Wh + (size_t)(m0 + row) * CDIM + kk + schk);
            sB[rnd] = *reinterpret_cast<const f16x8*>(
                xb + (size_t)(n0 + row) * CDIM + kk + schk);
        }
    };
    auto dswrite = [&](int buf) {
#pragma unroll
        for (int rnd = 0; rnd < 2; ++rnd) {
            const int row = srow + rnd * 64;
            *reinterpret_cast<f16x8*>(&As[buf][row * 32 + schk]) = sA[rnd];
            *reinterpret_cast<f16x8*>(&Bs[buf][row * 32 + schk]) = sB[rnd];
        }
    };

    f32x4 acc[4][4];
#pragma unroll
    for (int it = 0; it < 4; ++it)
#pragma unroll
        for (int ct = 0; ct < 4; ++ct) {
            f32x4 z = {0.f, 0.f, 0.f, 0.f};
            acc[it][ct] = z;
        }

    auto compute = [&](int buf) {
        f16x8 a[4], bf[4];
#pragma unroll
        for (int it = 0; it < 4; ++it)
            a[it] = *reinterpret_cast<const f16x8*>(
                &As[buf][(wr * 64 + it * 16 + lr) * 32 + 8 * g]);
#pragma unroll
        for (int ct = 0; ct < 4; ++ct)
            bf[ct] = *reinterpret_cast<const f16x8*>(
                &Bs[buf][(wc * 64 + ct * 16 + lr) * 32 + 8 * g]);
#pragma unroll
        for (int it = 0; it < 4; ++it)
#pragma unroll
            for (int ct = 0; ct < 4; ++ct)
                acc[it][ct] = __builtin_amdgcn_mfma_f32_16x16x32_f16(a[it], bf[ct], acc[it][ct], 0, 0, 0);
    };

    gload(0);
    dswrite(0);
    __syncthreads();

#pragma unroll 1
    for (int t = 0; t < 16; ++t) {
        if (t < 15) gload((t + 1) * 32);
        compute(t & 1);
        if (t < 15) dswrite((t + 1) & 1);
        __syncthreads();
    }

    if (m0 == 0) {
        _Float16* dst = (wr == 0) ? Qp : Kp;
#pragma unroll
        for (int it = 0; it < 4; ++it) {
            const int gmb = m0 + wr * 64 + it * 16 + 4 * g;
            const int ob  = gmb & 63;
#pragma unroll
            for (int ct = 0; ct < 4; ++ct) {
                const int n = n0 + wc * 64 + ct * 16 + lr;
                f16x4 h;
#pragma unroll
                for (int r = 0; r < 4; ++r)
                    h[r] = (_Float16)(acc[it][ct][r] + biasc[gmb + r]);
                *reinterpret_cast<f16x4*>(dst + ((size_t)b * NPOS + n) * CQK + ob) = h;
            }
        }
    } else {
#pragma unroll
        for (int it = 0; it < 4; ++it) {
            const int gmb = m0 + wr * 64 + it * 16 + 4 * g;
#pragma unroll
            for (int ct = 0; ct < 4; ++ct) {
                const int n = n0 + wc * 64 + ct * 16 + lr;
#pragma unroll
                for (int r = 0; r < 4; ++r) {
                    const int c = gmb + r - 128;
                    Vp[((size_t)b * CDIM + c) * NPOS + n] =
                        (_Float16)(acc[it][ct][r] + biasc[gmb + r]);
                }
            }
        }
    }
}

// ---------------- Fused attention: pass 1 (row max + sum-exp) + pass 2 (flash PV) ----------------
// One block = 64 q-rows x all 512 c x all 4096 j. Pass 1 runs the SAME swapped E chain
// (mfma(K,Q)) as pass 2 over all 32 chunks with online (m,l) per lane, reduces across
// g (2 shfl) and waves (LDS), and parks per-row (m,l) in LDS. Pass 2 is the R16 schedule
// verbatim, reading m from LDS; epilogue reads l from LDS. Bitwise-E between passes is
// trivially exact (same instructions, same operands in one kernel) -> exp(E-m) <= 1.
// Deletes the stats dispatch + mArr/lArr global round-trip.
__global__ __launch_bounds__(512, 2) void attn_fused_kernel(
    const float* __restrict__ x, const _Float16* __restrict__ Qp, const _Float16* __restrict__ Kp,
    const _Float16* __restrict__ Vp, const float* __restrict__ gamma, float* __restrict__ out)
{
    __shared__ __align__(16) _Float16 Pl[2][64 * 128];
    __shared__ float lmw[8 * 64];
    __shared__ float lsw[8 * 64];
    __shared__ float mfin[64];
    __shared__ float lfin[64];
    char* pb0 = (char*)Pl[0];
    char* pb1 = (char*)Pl[1];

    const int tid  = threadIdx.x;
    const int lane = tid & 63;
    const int w    = tid >> 6;      // 0..7
    const int g    = lane >> 4;     // 0..3
    const int lr   = lane & 15;

    // XCD-aware decode: batch b -> XCDs {2b,2b+1} so each XCD L2 holds one batch's V+K.
    const int bid = blockIdx.x;
    const int b   = (bid & 7) >> 1;
    const int ib  = (((bid >> 3) << 1) | (bid & 1)) * 64;
    const int cw  = w * 64;

    const _Float16* kb = Kp + (size_t)b * NPOS * CQK;
    const _Float16* vb = Vp + (size_t)b * CDIM * NPOS;

    f16x8 qf[4][2];
#pragma unroll
    for (int it = 0; it < 4; ++it)
#pragma unroll
        for (int ks = 0; ks < 2; ++ks)
            qf[it][ks] = *reinterpret_cast<const f16x8*>(
                Qp + (b * NPOS + ib + it * 16 + lr) * CQK + ks * 32 + 8 * g);

    f16x8 kA0, kA1, kB0, kB1;   // 2-slot K prefetch (shared by both passes)
    auto loadK = [&](int t, f16x8& k0, f16x8& k1) {
        const int tc = (t < 32) ? t : 31;
        const int j = tc * 128 + w * 16 + lr;
        k0 = *reinterpret_cast<const f16x8*>(kb + j * CQK + 8 * g);
        k1 = *reinterpret_cast<const f16x8*>(kb + j * CQK + 32 + 8 * g);
    };

    // ======== PASS 1: online (m, l) over all chunks, swapped E chain ========
    {
        float mrun[4][4], srun[4][4];
#pragma unroll
        for (int it = 0; it < 4; ++it)
#pragma unroll
            for (int r = 0; r < 4; ++r) { mrun[it][r] = -1e30f; srun[it][r] = 0.f; }

        auto step = [&](const f16x8& k0, const f16x8& k1) {
#pragma unroll
            for (int it = 0; it < 4; ++it) {
                f32x4 e = {0.f, 0.f, 0.f, 0.f};
                e = __builtin_amdgcn_mfma_f32_16x16x32_f16(k0, qf[it][0], e, 0, 0, 0);
                e = __builtin_amdgcn_mfma_f32_16x16x32_f16(k1, qf[it][1], e, 0, 0, 0);
#pragma unroll
                for (int r = 0; r < 4; ++r) {
                    const float ev = e[r];
                    const float mo = mrun[it][r];
                    if (ev > mo) {
                        srun[it][r] = srun[it][r] * exp2f((mo - ev) * L2E) + 1.0f;
                        mrun[it][r] = ev;
                    } else {
                        srun[it][r] += exp2f((ev - mo) * L2E);
                    }
                }
            }
        };

        loadK(0, kA0, kA1);
#pragma unroll 1
        for (int tp = 0; tp < 16; ++tp) {
            const int t = 2 * tp;
            loadK(t + 1, kB0, kB1);
            step(kA0, kA1);
            loadK(t + 2, kA0, kA1);
            step(kB0, kB1);
        }

        // merge 4 in-lane j's, then across g (lanes lr, lr+16, lr+32, lr+48)
#pragma unroll
        for (int it = 0; it < 4; ++it) {
            float m = mrun[it][0], s = srun[it][0];
#pragma unroll
            for (int r = 1; r < 4; ++r) {
                const float mn = fmaxf(m, mrun[it][r]);
                s = s * exp2f((m - mn) * L2E) + srun[it][r] * exp2f((mrun[it][r] - mn) * L2E);
                m = mn;
            }
#pragma unroll
            for (int mask = 16; mask < 64; mask <<= 1) {
                float om = __shfl_xor(m, mask, 64);
                float os = __shfl_xor(s, mask, 64);
                float mn = fmaxf(m, om);
                s = s * exp2f((m - mn) * L2E) + os * exp2f((om - mn) * L2E);
                m = mn;
            }
            if (g == 0) {
                const int row = it * 16 + lr;
                lmw[w * 64 + row] = m;
                lsw[w * 64 + row] = s;
            }
        }
        __syncthreads();

        if (tid < 64) {
            float mm = lmw[tid];
#pragma unroll
            for (int w2 = 1; w2 < 8; ++w2) mm = fmaxf(mm, lmw[w2 * 64 + tid]);
            float ss = 0.f;
#pragma unroll
            for (int w2 = 0; w2 < 8; ++w2) ss += lsw[w2 * 64 + tid] * exp2f((lmw[w2 * 64 + tid] - mm) * L2E);
            mfin[tid] = mm;
            lfin[tid] = ss;
        }
        __syncthreads();
    }

    // m for row i = ib + it*16 + lr
    float mreg[4];
#pragma unroll
    for (int it = 0; it < 4; ++it)
        mreg[it] = mfin[it * 16 + lr];

    // ======== PASS 2: flash PV (R16 schedule verbatim) ========
    f32x4 acc[4][4];
#pragma unroll
    for (int it = 0; it < 4; ++it)
#pragma unroll
        for (int ct = 0; ct < 4; ++ct) {
            f32x4 z = {0.f, 0.f, 0.f, 0.f};
            acc[it][ct] = z;
        }

    f16x8 vA[2][4], vB[2][4];   // half-chunk V buffers (ks 0-1 / ks 2-3), 32 VGPR each

    auto loadVh = [&](int t, int h, f16x8 (&vr)[2][4]) {
        const int tc = (t < 32) ? t : 31;
        const int jb = tc * 128;
#pragma unroll
        for (int ks2 = 0; ks2 < 2; ++ks2)
#pragma unroll
            for (int ct = 0; ct < 4; ++ct)
                vr[ks2][ct] = *reinterpret_cast<const f16x8*>(
                    vb + (size_t)(cw + ct * 16 + lr) * NPOS + jb + (2 * h + ks2) * 32 + 8 * g);
    };
    // E phase (SWAPPED): e = mfma(K, Q) -> lane lr holds row i = it*16+lr,
    // cols j = w*16 + 4g + {0..3} -> one packed f16x4 (8B) LDS write per it.
    auto ephase = [&](const f16x8& k0, const f16x8& k1, char* dst) {
#pragma unroll
        for (int it = 0; it < 4; ++it) {
            f32x4 e = {0.f, 0.f, 0.f, 0.f};
            e = __builtin_amdgcn_mfma_f32_16x16x32_f16(k0, qf[it][0], e, 0, 0, 0);
            e = __builtin_amdgcn_mfma_f32_16x16x32_f16(k1, qf[it][1], e, 0, 0, 0);
            f16x4 p;
#pragma unroll
            for (int r = 0; r < 4; ++r)
                p[r] = (_Float16)exp2f((e[r] - mreg[it]) * L2E);
            const int i   = it * 16 + lr;
            const int off = (i * 256 + (w * 32 + 8 * g)) ^ ((i & 15) << 4);
            *reinterpret_cast<f16x4*>(dst + off) = p;
        }
    };
    auto pvhalf = [&](const char* src, int h, const f16x8 (&vr)[2][4]) {
        __builtin_amdgcn_s_setprio(1);
#pragma unroll
        for (int ks2 = 0; ks2 < 2; ++ks2) {
            const int ks = 2 * h + ks2;
            f16x8 pa[4];
#pragma unroll
            for (int it = 0; it < 4; ++it) {
                const int off = (it * 16 + lr) * 256 + ((ks * 64 + g * 16) ^ (lr << 4));
                pa[it] = *reinterpret_cast<const f16x8*>(src + off);
            }
#pragma unroll
            for (int it = 0; it < 4; ++it)
#pragma unroll
                for (int ct = 0; ct < 4; ++ct)
                    acc[it][ct] = __builtin_amdgcn_mfma_f32_16x16x32_f16(pa[it], vr[ks2][ct], acc[it][ct], 0, 0, 0);
        }
        __builtin_amdgcn_s_setprio(0);
    };

    auto region = [&](int t, char* rbuf, char* wbuf, f16x8& ku0, f16x8& ku1,
                      f16x8& kl0, f16x8& kl1) {
        ephase(ku0, ku1, wbuf);         // P(t+1) using K(t+1)
        loadK(t + 2, kl0, kl1);         // K(t+2) into the other slot
        pvhalf(rbuf, 0, vA);            // PV(t) ks 0-1
        loadVh(t + 1, 0, vA);           // V(t+1) ks 0-1
        pvhalf(rbuf, 1, vB);            // PV(t) ks 2-3
        loadVh(t + 1, 1, vB);           // V(t+1) ks 2-3
        LDS_BARRIER();
    };

    // Prologue: P(0) -> pb0, V(0) -> vA/vB, K(1) -> kA.
    loadK(0, kA0, kA1);
    loadVh(0, 0, vA);
    loadVh(0, 1, vB);
    ephase(kA0, kA1, pb0);              // P(0) (uses K(0) in kA)
    loadK(1, kA0, kA1);                 // K(1) -> kA (K(0) dead)
    __syncthreads();

#pragma unroll 1
    for (int tp = 0; tp < 16; ++tp) {
        const int t = 2 * tp;
        region(t,     pb0, pb1, kA0, kA1, kB0, kB1);   // chunk t:   P in pb0, K(t+1)=kA
        region(t + 1, pb1, pb0, kB0, kB1, kA0, kA1);   // chunk t+1: P in pb1, K(t+2)=kB
    }
    // (final region's ephase/loadK/loadV are tail-clamped and harmless; all 32 chunks PV'd)

    // ---- epilogue: out = gamma * acc / l + x (l from LDS) ----
    const float gm = gamma[0];
#pragma unroll
    for (int it = 0; it < 4; ++it) {
        const int rb = it * 16 + 4 * g;     // local row base for this lane's acc
        const int idx = ib + rb;
        float inv[4];
#pragma unroll
        for (int r = 0; r < 4; ++r)
            inv[r] = 1.0f / lfin[rb + r];
#pragma unroll
        for (int ct = 0; ct < 4; ++ct) {
            const int c = cw + ct * 16 + lr;
            const size_t base = (size_t)(b * CDIM + c) * NPOS + idx;
            const float4 xv = *reinterpret_cast<const float4*>(x + base);
            float4 ov;
            ov.x = gm * (acc[it][ct][0] * inv[0]) + xv.x;
            ov.y = gm * (acc[it][ct][1] * inv[1]) + xv.y;
            ov.z = gm * (acc[it][ct][2] * inv[2]) + xv.z;
            ov.w = gm * (acc[it][ct][3] * inv[3]) + xv.w;
            *reinterpret_cast<float4*>(out + base) = ov;
        }
    }
}

extern "C" void kernel_launch(void* const* d_in, const int* in_sizes, int n_in,
                              void* d_out, int out_size, void* d_ws, size_t ws_size,
                              hipStream_t stream)
{
    (void)in_sizes; (void)n_in; (void)out_size; (void)ws_size;

    const float* x     = (const float*)d_in[0];
    const float* wq    = (const float*)d_in[1];
    const float* bq    = (const float*)d_in[2];
    const float* wk    = (const float*)d_in[3];
    const float* bk    = (const float*)d_in[4];
    const float* wv    = (const float*)d_in[5];
    const float* bv    = (const float*)d_in[6];
    const float* gamma = (const float*)d_in[7];
    float* out = (float*)d_out;

    char* ws = (char*)d_ws;
    const size_t qkBytes = (size_t)NBATCH * NPOS * CQK * sizeof(_Float16);     //  2 MiB each
    const size_t vBytes  = (size_t)NBATCH * CDIM * NPOS * sizeof(_Float16);    // 16 MiB
    const size_t xtBytes = (size_t)NBATCH * NPOS * CDIM * sizeof(_Float16);    // 16 MiB

    _Float16* Qp = (_Float16*)(ws);
    _Float16* Kp = (_Float16*)(ws + qkBytes);
    _Float16* Vp = (_Float16*)(ws + 2 * qkBytes);
    _Float16* Xt = (_Float16*)(ws + 2 * qkBytes + vBytes);
    _Float16* Wh = (_Float16*)(ws + 2 * qkBytes + vBytes + xtBytes);
    float* biasc = (float*)(ws + 2 * qkBytes + vBytes + xtBytes
                              + (size_t)640 * CDIM * sizeof(_Float16));
    // total ws use ~= 36.6 MiB

    w_cvt_kernel<<<dim3(640 * CDIM / 4 / 256), 256, 0, stream>>>(wq, bq, wk, bk, wv, bv, Wh, biasc);
    x_cvt_kernel<<<dim3(NPOS / 64, CDIM / 64, NBATCH), 256, 0, stream>>>(x, Xt);
    proj_gemm_kernel<<<dim3(NPOS / 128, 5, NBATCH), 256, 0, stream>>>(Wh, biasc, Xt, Qp, Kp, Vp);
    attn_fused_kernel<<<dim3(NPOS / 64 * NBATCH), 512, 0, stream>>>(x, Qp, Kp, Vp, gamma, out);
}

// Round 18
// 198.057 us; speedup vs baseline: 1.1481x; 1.1481x over previous
//
#include <hip/hip_runtime.h>
#include <hip/hip_fp16.h>

#define NPOS   4096
#define CDIM   512
#define CQK    64
#define NBATCH 4
#define L2E 1.44269504088896f

typedef _Float16 f16x8 __attribute__((ext_vector_type(8)));
typedef _Float16 f16x4 __attribute__((ext_vector_type(4)));
typedef float    f32x4 __attribute__((ext_vector_type(4)));

// LDS-only drain barrier: keeps global-load (vmcnt) prefetches in flight across
// the barrier (T4). All cross-wave traffic here is LDS, so lgkmcnt(0) suffices.
#define LDS_BARRIER() asm volatile("s_waitcnt lgkmcnt(0)\ns_barrier" ::: "memory")

// ---------------- x convert+transpose: x[b,c,n] f32 -> Xt[b,n,c] f16 ----------------
__global__ __launch_bounds__(256) void x_cvt_kernel(
    const float* __restrict__ x, _Float16* __restrict__ Xt)
{
    __shared__ _Float16 tile[64][66];
    const int b  = blockIdx.z;
    const int c0 = blockIdx.y * 64;
    const int n0 = blockIdx.x * 64;
    const int tid = threadIdx.x;

    const int rr = tid >> 4;
    const int n4 = (tid & 15) * 4;
#pragma unroll
    for (int i = 0; i < 4; ++i) {
        const int c = i * 16 + rr;
        const float4 v = *reinterpret_cast<const float4*>(
            x + (size_t)(b * CDIM + c0 + c) * NPOS + n0 + n4);
        tile[c][n4 + 0] = (_Float16)v.x;
        tile[c][n4 + 1] = (_Float16)v.y;
        tile[c][n4 + 2] = (_Float16)v.z;
        tile[c][n4 + 3] = (_Float16)v.w;
    }
    __syncthreads();

    const int col = tid & 63;
    const int r4  = tid >> 6;
#pragma unroll
    for (int i = 0; i < 16; ++i) {
        const int n = i * 4 + r4;
        Xt[((size_t)b * NPOS + n0 + n) * CDIM + c0 + col] = tile[col][n];
    }
}

// ---------------- weight convert ----------------
__global__ __launch_bounds__(256) void w_cvt_kernel(
    const float* __restrict__ wq, const float* __restrict__ bq,
    const float* __restrict__ wk, const float* __restrict__ bk,
    const float* __restrict__ wv, const float* __restrict__ bv,
    _Float16* __restrict__ Wh, float* __restrict__ biasc)
{
    const int gid = blockIdx.x * 256 + threadIdx.x;
    const int idx = gid * 4;
    const float* src;
    if (idx < 64 * 512)       src = wq + idx;
    else if (idx < 128 * 512) src = wk + (idx - 64 * 512);
    else                      src = wv + (idx - 128 * 512);
    const float4 v = *reinterpret_cast<const float4*>(src);
    f16x4 h;
    h[0] = (_Float16)v.x; h[1] = (_Float16)v.y;
    h[2] = (_Float16)v.z; h[3] = (_Float16)v.w;
    *reinterpret_cast<f16x4*>(Wh + idx) = h;
    if (gid < 640) {
        float bb;
        if (gid < 64)       bb = bq[gid];
        else if (gid < 128) bb = bk[gid - 64];
        else                bb = bv[gid - 128];
        biasc[gid] = bb;
    }
}

// ---------------- fused QKV projection GEMM: 128x128 tile, LDS double-buffered ----------------
// (R13 structure — measured best; unchanged.)
__global__ __launch_bounds__(256) void proj_gemm_kernel(
    const _Float16* __restrict__ Wh, const float* __restrict__ biasc,
    const _Float16* __restrict__ Xt,
    _Float16* __restrict__ Qp, _Float16* __restrict__ Kp, _Float16* __restrict__ Vp)
{
    __shared__ __align__(16) _Float16 As[2][128 * 32];
    __shared__ __align__(16) _Float16 Bs[2][128 * 32];

    const int tid  = threadIdx.x;
    const int lane = tid & 63;
    const int w    = tid >> 6;       // 0..3
    const int wr   = w >> 1;         // m-half
    const int wc   = w & 1;          // n-half
    const int g    = lane >> 4;
    const int lr   = lane & 15;

    const int b  = blockIdx.z;
    const int m0 = blockIdx.y * 128;
    const int n0 = blockIdx.x * 128;

    const _Float16* xb = Xt + (size_t)b * NPOS * CDIM;

    const int srow = tid >> 2;
    const int schk = (tid & 3) * 8;

    f16x8 sA[2], sB[2];
    auto gload = [&](int kk) {
#pragma unroll
        for (int rnd = 0; rnd < 2; ++rnd) {
            const int row = srow + rnd * 64;
            sA[rnd] = *reinterpret_cast<const f16x8*>(
                Wh + (size_t)(m0 + row) * CDIM + kk + schk);
            sB[rnd] = *reinterpret_cast<const f16x8*>(
                xb + (size_t)(n0 + row) * CDIM + kk + schk);
        }
    };
    auto dswrite = [&](int buf) {
#pragma unroll
        for (int rnd = 0; rnd < 2; ++rnd) {
            const int row = srow + rnd * 64;
            *reinterpret_cast<f16x8*>(&As[buf][row * 32 + schk]) = sA[rnd];
            *reinterpret_cast<f16x8*>(&Bs[buf][row * 32 + schk]) = sB[rnd];
        }
    };

    f32x4 acc[4][4];
#pragma unroll
    for (int it = 0; it < 4; ++it)
#pragma unroll
        for (int ct = 0; ct < 4; ++ct) {
            f32x4 z = {0.f, 0.f, 0.f, 0.f};
            acc[it][ct] = z;
        }

    auto compute = [&](int buf) {
        f16x8 a[4], bf[4];
#pragma unroll
        for (int it = 0; it < 4; ++it)
            a[it] = *reinterpret_cast<const f16x8*>(
                &As[buf][(wr * 64 + it * 16 + lr) * 32 + 8 * g]);
#pragma unroll
        for (int ct = 0; ct < 4; ++ct)
            bf[ct] = *reinterpret_cast<const f16x8*>(
                &Bs[buf][(wc * 64 + ct * 16 + lr) * 32 + 8 * g]);
#pragma unroll
        for (int it = 0; it < 4; ++it)
#pragma unroll
            for (int ct = 0; ct < 4; ++ct)
                acc[it][ct] = __builtin_amdgcn_mfma_f32_16x16x32_f16(a[it], bf[ct], acc[it][ct], 0, 0, 0);
    };

    gload(0);
    dswrite(0);
    __syncthreads();

#pragma unroll 1
    for (int t = 0; t < 16; ++t) {
        if (t < 15) gload((t + 1) * 32);
        compute(t & 1);
        if (t < 15) dswrite((t + 1) & 1);
        __syncthreads();
    }

    if (m0 == 0) {
        _Float16* dst = (wr == 0) ? Qp : Kp;
#pragma unroll
        for (int it = 0; it < 4; ++it) {
            const int gmb = m0 + wr * 64 + it * 16 + 4 * g;
            const int ob  = gmb & 63;
#pragma unroll
            for (int ct = 0; ct < 4; ++ct) {
                const int n = n0 + wc * 64 + ct * 16 + lr;
                f16x4 h;
#pragma unroll
                for (int r = 0; r < 4; ++r)
                    h[r] = (_Float16)(acc[it][ct][r] + biasc[gmb + r]);
                *reinterpret_cast<f16x4*>(dst + ((size_t)b * NPOS + n) * CQK + ob) = h;
            }
        }
    } else {
#pragma unroll
        for (int it = 0; it < 4; ++it) {
            const int gmb = m0 + wr * 64 + it * 16 + 4 * g;
#pragma unroll
            for (int ct = 0; ct < 4; ++ct) {
                const int n = n0 + wc * 64 + ct * 16 + lr;
#pragma unroll
                for (int r = 0; r < 4; ++r) {
                    const int c = gmb + r - 128;
                    Vp[((size_t)b * CDIM + c) * NPOS + n] =
                        (_Float16)(acc[it][ct][r] + biasc[gmb + r]);
                }
            }
        }
    }
}

// ---------------- Fused attention: pass 1 (row MAX only) + pass 2 (flash PV + l-from-P) ----------------
// Pass 1: same swapped E chain (mfma(K,Q)) over all 32 chunks, but MAX-ONLY — no exp,
// no branchy online update (that VALU was the R17 regression: VALUBusy 32%). Reduce max
// across r (in-lane), g (2 shfl), waves (LDS) -> mfin.
// Pass 2: R16 schedule verbatim; ephase additionally accumulates lrun[it] += sum of the
// 4 f16 P values it just computed (f32 adds, hidden under MFMA; guarded so the one
// tail-clamped duplicate ephase doesn't double-count). After the loop: reduce lrun
// across g/waves -> lfin; epilogue divides by it. The denominator is now the sum of
// exactly the f16 P values used in the numerator -> accuracy unchanged-or-better.
// Bitwise-E between passes trivially exact (same instructions, same kernel).
__global__ __launch_bounds__(512, 2) void attn_fused_kernel(
    const float* __restrict__ x, const _Float16* __restrict__ Qp, const _Float16* __restrict__ Kp,
    const _Float16* __restrict__ Vp, const float* __restrict__ gamma, float* __restrict__ out)
{
    __shared__ __align__(16) _Float16 Pl[2][64 * 128];
    __shared__ float lmw[8 * 64];
    __shared__ float mfin[64];
    __shared__ float lfin[64];
    char* pb0 = (char*)Pl[0];
    char* pb1 = (char*)Pl[1];

    const int tid  = threadIdx.x;
    const int lane = tid & 63;
    const int w    = tid >> 6;      // 0..7
    const int g    = lane >> 4;     // 0..3
    const int lr   = lane & 15;

    // XCD-aware decode: batch b -> XCDs {2b,2b+1} so each XCD L2 holds one batch's V+K.
    const int bid = blockIdx.x;
    const int b   = (bid & 7) >> 1;
    const int ib  = (((bid >> 3) << 1) | (bid & 1)) * 64;
    const int cw  = w * 64;

    const _Float16* kb = Kp + (size_t)b * NPOS * CQK;
    const _Float16* vb = Vp + (size_t)b * CDIM * NPOS;

    f16x8 qf[4][2];
#pragma unroll
    for (int it = 0; it < 4; ++it)
#pragma unroll
        for (int ks = 0; ks < 2; ++ks)
            qf[it][ks] = *reinterpret_cast<const f16x8*>(
                Qp + (b * NPOS + ib + it * 16 + lr) * CQK + ks * 32 + 8 * g);

    f16x8 kA0, kA1, kB0, kB1;   // 2-slot K prefetch (shared by both passes)
    auto loadK = [&](int t, f16x8& k0, f16x8& k1) {
        const int tc = (t < 32) ? t : 31;
        const int j = tc * 128 + w * 16 + lr;
        k0 = *reinterpret_cast<const f16x8*>(kb + j * CQK + 8 * g);
        k1 = *reinterpret_cast<const f16x8*>(kb + j * CQK + 32 + 8 * g);
    };

    // ======== PASS 1: row max only (cheap VALU: 4 fmax-trees per chunk) ========
    {
        float mrun[4];
#pragma unroll
        for (int it = 0; it < 4; ++it) mrun[it] = -1e30f;

        auto step = [&](const f16x8& k0, const f16x8& k1) {
#pragma unroll
            for (int it = 0; it < 4; ++it) {
                f32x4 e = {0.f, 0.f, 0.f, 0.f};
                e = __builtin_amdgcn_mfma_f32_16x16x32_f16(k0, qf[it][0], e, 0, 0, 0);
                e = __builtin_amdgcn_mfma_f32_16x16x32_f16(k1, qf[it][1], e, 0, 0, 0);
                mrun[it] = fmaxf(mrun[it],
                                 fmaxf(fmaxf(e[0], e[1]), fmaxf(e[2], e[3])));
            }
        };

        loadK(0, kA0, kA1);
#pragma unroll 1
        for (int tp = 0; tp < 16; ++tp) {
            const int t = 2 * tp;
            loadK(t + 1, kB0, kB1);
            step(kA0, kA1);
            loadK(t + 2, kA0, kA1);
            step(kB0, kB1);
        }

        // reduce across g (lanes lr, lr+16, lr+32, lr+48), then across waves via LDS
#pragma unroll
        for (int it = 0; it < 4; ++it) {
            float m = mrun[it];
#pragma unroll
            for (int mask = 16; mask < 64; mask <<= 1)
                m = fmaxf(m, __shfl_xor(m, mask, 64));
            if (g == 0)
                lmw[w * 64 + it * 16 + lr] = m;
        }
        __syncthreads();

        if (tid < 64) {
            float mm = lmw[tid];
#pragma unroll
            for (int w2 = 1; w2 < 8; ++w2) mm = fmaxf(mm, lmw[w2 * 64 + tid]);
            mfin[tid] = mm;
        }
        __syncthreads();
    }

    // m for row i = ib + it*16 + lr
    float mreg[4];
#pragma unroll
    for (int it = 0; it < 4; ++it)
        mreg[it] = mfin[it * 16 + lr];

    // ======== PASS 2: flash PV (R16 schedule) + l accumulation from P ========
    f32x4 acc[4][4];
#pragma unroll
    for (int it = 0; it < 4; ++it)
#pragma unroll
        for (int ct = 0; ct < 4; ++ct) {
            f32x4 z = {0.f, 0.f, 0.f, 0.f};
            acc[it][ct] = z;
        }

    float lrun[4] = {0.f, 0.f, 0.f, 0.f};   // per-lane partial sums of P
    f16x8 vA[2][4], vB[2][4];   // half-chunk V buffers (ks 0-1 / ks 2-3), 32 VGPR each

    auto loadVh = [&](int t, int h, f16x8 (&vr)[2][4]) {
        const int tc = (t < 32) ? t : 31;
        const int jb = tc * 128;
#pragma unroll
        for (int ks2 = 0; ks2 < 2; ++ks2)
#pragma unroll
            for (int ct = 0; ct < 4; ++ct)
                vr[ks2][ct] = *reinterpret_cast<const f16x8*>(
                    vb + (size_t)(cw + ct * 16 + lr) * NPOS + jb + (2 * h + ks2) * 32 + 8 * g);
    };
    // E phase (SWAPPED): lane lr holds row i = it*16+lr, cols j = w*16+4g+{0..3}
    // -> one packed f16x4 LDS write per it. live=false for the tail-clamped duplicate
    // call (chunk index 32) so l isn't double-counted.
    auto ephase = [&](const f16x8& k0, const f16x8& k1, char* dst, bool live) {
#pragma unroll
        for (int it = 0; it < 4; ++it) {
            f32x4 e = {0.f, 0.f, 0.f, 0.f};
            e = __builtin_amdgcn_mfma_f32_16x16x32_f16(k0, qf[it][0], e, 0, 0, 0);
            e = __builtin_amdgcn_mfma_f32_16x16x32_f16(k1, qf[it][1], e, 0, 0, 0);
            f16x4 p;
#pragma unroll
            for (int r = 0; r < 4; ++r)
                p[r] = (_Float16)exp2f((e[r] - mreg[it]) * L2E);
            if (live)
                lrun[it] += (float)p[0] + (float)p[1] + (float)p[2] + (float)p[3];
            const int i   = it * 16 + lr;
            const int off = (i * 256 + (w * 32 + 8 * g)) ^ ((i & 15) << 4);
            *reinterpret_cast<f16x4*>(dst + off) = p;
        }
    };
    auto pvhalf = [&](const char* src, int h, const f16x8 (&vr)[2][4]) {
        __builtin_amdgcn_s_setprio(1);
#pragma unroll
        for (int ks2 = 0; ks2 < 2; ++ks2) {
            const int ks = 2 * h + ks2;
            f16x8 pa[4];
#pragma unroll
            for (int it = 0; it < 4; ++it) {
                const int off = (it * 16 + lr) * 256 + ((ks * 64 + g * 16) ^ (lr << 4));
                pa[it] = *reinterpret_cast<const f16x8*>(src + off);
            }
#pragma unroll
            for (int it = 0; it < 4; ++it)
#pragma unroll
                for (int ct = 0; ct < 4; ++ct)
                    acc[it][ct] = __builtin_amdgcn_mfma_f32_16x16x32_f16(pa[it], vr[ks2][ct], acc[it][ct], 0, 0, 0);
        }
        __builtin_amdgcn_s_setprio(0);
    };

    auto region = [&](int t, char* rbuf, char* wbuf, f16x8& ku0, f16x8& ku1,
                      f16x8& kl0, f16x8& kl1) {
        ephase(ku0, ku1, wbuf, (t + 1) < 32);   // P(t+1) using K(t+1)
        loadK(t + 2, kl0, kl1);                 // K(t+2) into the other slot
        pvhalf(rbuf, 0, vA);                    // PV(t) ks 0-1
        loadVh(t + 1, 0, vA);                   // V(t+1) ks 0-1
        pvhalf(rbuf, 1, vB);                    // PV(t) ks 2-3
        loadVh(t + 1, 1, vB);                   // V(t+1) ks 2-3
        LDS_BARRIER();
    };

    // Prologue: P(0) -> pb0, V(0) -> vA/vB, K(1) -> kA.
    loadK(0, kA0, kA1);
    loadVh(0, 0, vA);
    loadVh(0, 1, vB);
    ephase(kA0, kA1, pb0, true);        // P(0) (uses K(0) in kA)
    loadK(1, kA0, kA1);                 // K(1) -> kA (K(0) dead)
    __syncthreads();

#pragma unroll 1
    for (int tp = 0; tp < 16; ++tp) {
        const int t = 2 * tp;
        region(t,     pb0, pb1, kA0, kA1, kB0, kB1);   // chunk t:   P in pb0, K(t+1)=kA
        region(t + 1, pb1, pb0, kB0, kB1, kA0, kA1);   // chunk t+1: P in pb1, K(t+2)=kB
    }
    // (final region's ephase is live=false; all 32 chunks PV'd and l-counted once)

    // ---- reduce l across g and waves ----
#pragma unroll
    for (int it = 0; it < 4; ++it) {
        float s = lrun[it];
#pragma unroll
        for (int mask = 16; mask < 64; mask <<= 1)
            s += __shfl_xor(s, mask, 64);
        if (g == 0)
            lmw[w * 64 + it * 16 + lr] = s;
    }
    __syncthreads();
    if (tid < 64) {
        float ss = 0.f;
#pragma unroll
        for (int w2 = 0; w2 < 8; ++w2) ss += lmw[w2 * 64 + tid];
        lfin[tid] = ss;
    }
    __syncthreads();

    // ---- epilogue: out = gamma * acc / l + x (l from LDS) ----
    const float gm = gamma[0];
#pragma unroll
    for (int it = 0; it < 4; ++it) {
        const int rb = it * 16 + 4 * g;     // local row base for this lane's acc
        const int idx = ib + rb;
        float inv[4];
#pragma unroll
        for (int r = 0; r < 4; ++r)
            inv[r] = 1.0f / lfin[rb + r];
#pragma unroll
        for (int ct = 0; ct < 4; ++ct) {
            const int c = cw + ct * 16 + lr;
            const size_t base = (size_t)(b * CDIM + c) * NPOS + idx;
            const float4 xv = *reinterpret_cast<const float4*>(x + base);
            float4 ov;
            ov.x = gm * (acc[it][ct][0] * inv[0]) + xv.x;
            ov.y = gm * (acc[it][ct][1] * inv[1]) + xv.y;
            ov.z = gm * (acc[it][ct][2] * inv[2]) + xv.z;
            ov.w = gm * (acc[it][ct][3] * inv[3]) + xv.w;
            *reinterpret_cast<float4*>(out + base) = ov;
        }
    }
}

extern "C" void kernel_launch(void* const* d_in, const int* in_sizes, int n_in,
                              void* d_out, int out_size, void* d_ws, size_t ws_size,
                              hipStream_t stream)
{
    (void)in_sizes; (void)n_in; (void)out_size; (void)ws_size;

    const float* x     = (const float*)d_in[0];
    const float* wq    = (const float*)d_in[1];
    const float* bq    = (const float*)d_in[2];
    const float* wk    = (const float*)d_in[3];
    const float* bk    = (const float*)d_in[4];
    const float* wv    = (const float*)d_in[5];
    const float* bv    = (const float*)d_in[6];
    const float* gamma = (const float*)d_in[7];
    float* out = (float*)d_out;

    char* ws = (char*)d_ws;
    const size_t qkBytes = (size_t)NBATCH * NPOS * CQK * sizeof(_Float16);     //  2 MiB each
    const size_t vBytes  = (size_t)NBATCH * CDIM * NPOS * sizeof(_Float16);    // 16 MiB
    const size_t xtBytes = (size_t)NBATCH * NPOS * CDIM * sizeof(_Float16);    // 16 MiB

    _Float16* Qp = (_Float16*)(ws);
    _Float16* Kp = (_Float16*)(ws + qkBytes);
    _Float16* Vp = (_Float16*)(ws + 2 * qkBytes);
    _Float16* Xt = (_Float16*)(ws + 2 * qkBytes + vBytes);
    _Float16* Wh = (_Float16*)(ws + 2 * qkBytes + vBytes + xtBytes);
    float* biasc = (float*)(ws + 2 * qkBytes + vBytes + xtBytes
                              + (size_t)640 * CDIM * sizeof(_Float16));
    // total ws use ~= 36.6 MiB

    w_cvt_kernel<<<dim3(640 * CDIM / 4 / 256), 256, 0, stream>>>(wq, bq, wk, bk, wv, bv, Wh, biasc);
    x_cvt_kernel<<<dim3(NPOS / 64, CDIM / 64, NBATCH), 256, 0, stream>>>(x, Xt);
    proj_gemm_kernel<<<dim3(NPOS / 128, 5, NBATCH), 256, 0, stream>>>(Wh, biasc, Xt, Qp, Kp, Vp);
    attn_fused_kernel<<<dim3(NPOS / 64 * NBATCH), 512, 0, stream>>>(x, Qp, Kp, Vp, gamma, out);
}

// Round 19
// 198.046 us; speedup vs baseline: 1.1482x; 1.0001x over previous
//
#include <hip/hip_runtime.h>
#include <hip/hip_fp16.h>

#define NPOS   4096
#define CDIM   512
#define CQK    64
#define NBATCH 4
#define L2E 1.44269504088896f

typedef _Float16 f16x8 __attribute__((ext_vector_type(8)));
typedef _Float16 f16x4 __attribute__((ext_vector_type(4)));
typedef float    f32x4 __attribute__((ext_vector_type(4)));

// LDS-only drain barrier: keeps global-load (vmcnt) prefetches in flight across
// the barrier (T4). All cross-wave traffic here is LDS, so lgkmcnt(0) suffices.
#define LDS_BARRIER() asm volatile("s_waitcnt lgkmcnt(0)\ns_barrier" ::: "memory")

// ---------------- x convert+transpose: x[b,c,n] f32 -> Xt[b,n,c] f16 ----------------
__global__ __launch_bounds__(256) void x_cvt_kernel(
    const float* __restrict__ x, _Float16* __restrict__ Xt)
{
    __shared__ _Float16 tile[64][66];
    const int b  = blockIdx.z;
    const int c0 = blockIdx.y * 64;
    const int n0 = blockIdx.x * 64;
    const int tid = threadIdx.x;

    const int rr = tid >> 4;
    const int n4 = (tid & 15) * 4;
#pragma unroll
    for (int i = 0; i < 4; ++i) {
        const int c = i * 16 + rr;
        const float4 v = *reinterpret_cast<const float4*>(
            x + (size_t)(b * CDIM + c0 + c) * NPOS + n0 + n4);
        tile[c][n4 + 0] = (_Float16)v.x;
        tile[c][n4 + 1] = (_Float16)v.y;
        tile[c][n4 + 2] = (_Float16)v.z;
        tile[c][n4 + 3] = (_Float16)v.w;
    }
    __syncthreads();

    const int col = tid & 63;
    const int r4  = tid >> 6;
#pragma unroll
    for (int i = 0; i < 16; ++i) {
        const int n = i * 4 + r4;
        Xt[((size_t)b * NPOS + n0 + n) * CDIM + c0 + col] = tile[col][n];
    }
}

// ---------------- weight convert ----------------
__global__ __launch_bounds__(256) void w_cvt_kernel(
    const float* __restrict__ wq, const float* __restrict__ bq,
    const float* __restrict__ wk, const float* __restrict__ bk,
    const float* __restrict__ wv, const float* __restrict__ bv,
    _Float16* __restrict__ Wh, float* __restrict__ biasc)
{
    const int gid = blockIdx.x * 256 + threadIdx.x;
    const int idx = gid * 4;
    const float* src;
    if (idx < 64 * 512)       src = wq + idx;
    else if (idx < 128 * 512) src = wk + (idx - 64 * 512);
    else                      src = wv + (idx - 128 * 512);
    const float4 v = *reinterpret_cast<const float4*>(src);
    f16x4 h;
    h[0] = (_Float16)v.x; h[1] = (_Float16)v.y;
    h[2] = (_Float16)v.z; h[3] = (_Float16)v.w;
    *reinterpret_cast<f16x4*>(Wh + idx) = h;
    if (gid < 640) {
        float bb;
        if (gid < 64)       bb = bq[gid];
        else if (gid < 128) bb = bk[gid - 64];
        else                bb = bv[gid - 128];
        biasc[gid] = bb;
    }
}

// ---------------- fused QKV projection GEMM: 128x128 tile, LDS double-buffered ----------------
// (R13 structure — measured best; unchanged.)
__global__ __launch_bounds__(256) void proj_gemm_kernel(
    const _Float16* __restrict__ Wh, const float* __restrict__ biasc,
    const _Float16* __restrict__ Xt,
    _Float16* __restrict__ Qp, _Float16* __restrict__ Kp, _Float16* __restrict__ Vp)
{
    __shared__ __align__(16) _Float16 As[2][128 * 32];
    __shared__ __align__(16) _Float16 Bs[2][128 * 32];

    const int tid  = threadIdx.x;
    const int lane = tid & 63;
    const int w    = tid >> 6;       // 0..3
    const int wr   = w >> 1;         // m-half
    const int wc   = w & 1;          // n-half
    const int g    = lane >> 4;
    const int lr   = lane & 15;

    const int b  = blockIdx.z;
    const int m0 = blockIdx.y * 128;
    const int n0 = blockIdx.x * 128;

    const _Float16* xb = Xt + (size_t)b * NPOS * CDIM;

    const int srow = tid >> 2;
    const int schk = (tid & 3) * 8;

    f16x8 sA[2], sB[2];
    auto gload = [&](int kk) {
#pragma unroll
        for (int rnd = 0; rnd < 2; ++rnd) {
            const int row = srow + rnd * 64;
            sA[rnd] = *reinterpret_cast<const f16x8*>(
                Wh + (size_t)(m0 + row) * CDIM + kk + schk);
            sB[rnd] = *reinterpret_cast<const f16x8*>(
                xb + (size_t)(n0 + row) * CDIM + kk + schk);
        }
    };
    auto dswrite = [&](int buf) {
#pragma unroll
        for (int rnd = 0; rnd < 2; ++rnd) {
            const int row = srow + rnd * 64;
            *reinterpret_cast<f16x8*>(&As[buf][row * 32 + schk]) = sA[rnd];
            *reinterpret_cast<f16x8*>(&Bs[buf][row * 32 + schk]) = sB[rnd];
        }
    };

    f32x4 acc[4][4];
#pragma unroll
    for (int it = 0; it < 4; ++it)
#pragma unroll
        for (int ct = 0; ct < 4; ++ct) {
            f32x4 z = {0.f, 0.f, 0.f, 0.f};
            acc[it][ct] = z;
        }

    auto compute = [&](int buf) {
        f16x8 a[4], bf[4];
#pragma unroll
        for (int it = 0; it < 4; ++it)
            a[it] = *reinterpret_cast<const f16x8*>(
                &As[buf][(wr * 64 + it * 16 + lr) * 32 + 8 * g]);
#pragma unroll
        for (int ct = 0; ct < 4; ++ct)
            bf[ct] = *reinterpret_cast<const f16x8*>(
                &Bs[buf][(wc * 64 + ct * 16 + lr) * 32 + 8 * g]);
#pragma unroll
        for (int it = 0; it < 4; ++it)
#pragma unroll
            for (int ct = 0; ct < 4; ++ct)
                acc[it][ct] = __builtin_amdgcn_mfma_f32_16x16x32_f16(a[it], bf[ct], acc[it][ct], 0, 0, 0);
    };

    gload(0);
    dswrite(0);
    __syncthreads();

#pragma unroll 1
    for (int t = 0; t < 16; ++t) {
        if (t < 15) gload((t + 1) * 32);
        compute(t & 1);
        if (t < 15) dswrite((t + 1) & 1);
        __syncthreads();
    }

    if (m0 == 0) {
        _Float16* dst = (wr == 0) ? Qp : Kp;
#pragma unroll
        for (int it = 0; it < 4; ++it) {
            const int gmb = m0 + wr * 64 + it * 16 + 4 * g;
            const int ob  = gmb & 63;
#pragma unroll
            for (int ct = 0; ct < 4; ++ct) {
                const int n = n0 + wc * 64 + ct * 16 + lr;
                f16x4 h;
#pragma unroll
                for (int r = 0; r < 4; ++r)
                    h[r] = (_Float16)(acc[it][ct][r] + biasc[gmb + r]);
                *reinterpret_cast<f16x4*>(dst + ((size_t)b * NPOS + n) * CQK + ob) = h;
            }
        }
    } else {
#pragma unroll
        for (int it = 0; it < 4; ++it) {
            const int gmb = m0 + wr * 64 + it * 16 + 4 * g;
#pragma unroll
            for (int ct = 0; ct < 4; ++ct) {
                const int n = n0 + wc * 64 + ct * 16 + lr;
#pragma unroll
                for (int r = 0; r < 4; ++r) {
                    const int c = gmb + r - 128;
                    Vp[((size_t)b * CDIM + c) * NPOS + n] =
                        (_Float16)(acc[it][ct][r] + biasc[gmb + r]);
                }
            }
        }
    }
}

// ---------------- Fused attention: pass 1 (row MAX only, 4-deep K prefetch) + pass 2 ----------------
// Pass 1: swapped E chain (mfma(K,Q)) over all 32 chunks, MAX-ONLY, with a 4-SLOT K
// rotation (prefetch distance 4 chunks ~ 250+ cyc, covering the L2 round-trip that the
// 2-slot rotation exposed every chunk). Tail clamp is safe: duplicate chunk-31 fmax is
// idempotent. Pass-1 live set ~60 VGPR < pass-2 peak -> no allocation change.
// Pass 2: R18 schedule verbatim (flash PV + l accumulated from the f16 P values).
// Bitwise-E between passes trivially exact (same instructions, same kernel).
__global__ __launch_bounds__(512, 2) void attn_fused_kernel(
    const float* __restrict__ x, const _Float16* __restrict__ Qp, const _Float16* __restrict__ Kp,
    const _Float16* __restrict__ Vp, const float* __restrict__ gamma, float* __restrict__ out)
{
    __shared__ __align__(16) _Float16 Pl[2][64 * 128];
    __shared__ float lmw[8 * 64];
    __shared__ float mfin[64];
    __shared__ float lfin[64];
    char* pb0 = (char*)Pl[0];
    char* pb1 = (char*)Pl[1];

    const int tid  = threadIdx.x;
    const int lane = tid & 63;
    const int w    = tid >> 6;      // 0..7
    const int g    = lane >> 4;     // 0..3
    const int lr   = lane & 15;

    // XCD-aware decode: batch b -> XCDs {2b,2b+1} so each XCD L2 holds one batch's V+K.
    const int bid = blockIdx.x;
    const int b   = (bid & 7) >> 1;
    const int ib  = (((bid >> 3) << 1) | (bid & 1)) * 64;
    const int cw  = w * 64;

    const _Float16* kb = Kp + (size_t)b * NPOS * CQK;
    const _Float16* vb = Vp + (size_t)b * CDIM * NPOS;

    f16x8 qf[4][2];
#pragma unroll
    for (int it = 0; it < 4; ++it)
#pragma unroll
        for (int ks = 0; ks < 2; ++ks)
            qf[it][ks] = *reinterpret_cast<const f16x8*>(
                Qp + (b * NPOS + ib + it * 16 + lr) * CQK + ks * 32 + 8 * g);

    f16x8 kA0, kA1, kB0, kB1;   // 2-slot K prefetch (pass 2)
    auto loadK = [&](int t, f16x8& k0, f16x8& k1) {
        const int tc = (t < 32) ? t : 31;
        const int j = tc * 128 + w * 16 + lr;
        k0 = *reinterpret_cast<const f16x8*>(kb + j * CQK + 8 * g);
        k1 = *reinterpret_cast<const f16x8*>(kb + j * CQK + 32 + 8 * g);
    };

    // ======== PASS 1: row max only, 4-slot K rotation ========
    {
        float mrun[4];
#pragma unroll
        for (int it = 0; it < 4; ++it) mrun[it] = -1e30f;

        auto step = [&](const f16x8& k0, const f16x8& k1) {
#pragma unroll
            for (int it = 0; it < 4; ++it) {
                f32x4 e = {0.f, 0.f, 0.f, 0.f};
                e = __builtin_amdgcn_mfma_f32_16x16x32_f16(k0, qf[it][0], e, 0, 0, 0);
                e = __builtin_amdgcn_mfma_f32_16x16x32_f16(k1, qf[it][1], e, 0, 0, 0);
                mrun[it] = fmaxf(mrun[it],
                                 fmaxf(fmaxf(e[0], e[1]), fmaxf(e[2], e[3])));
            }
        };

        f16x8 kC0, kC1, kD0, kD1;   // extra slots, live only in pass 1
        loadK(0, kA0, kA1);
        loadK(1, kB0, kB1);
        loadK(2, kC0, kC1);
        loadK(3, kD0, kD1);
#pragma unroll 1
        for (int tp = 0; tp < 8; ++tp) {
            const int t = 4 * tp;
            step(kA0, kA1);  loadK(t + 4, kA0, kA1);
            step(kB0, kB1);  loadK(t + 5, kB0, kB1);
            step(kC0, kC1);  loadK(t + 6, kC0, kC1);
            step(kD0, kD1);  loadK(t + 7, kD0, kD1);
        }

        // reduce across g (lanes lr, lr+16, lr+32, lr+48), then across waves via LDS
#pragma unroll
        for (int it = 0; it < 4; ++it) {
            float m = mrun[it];
#pragma unroll
            for (int mask = 16; mask < 64; mask <<= 1)
                m = fmaxf(m, __shfl_xor(m, mask, 64));
            if (g == 0)
                lmw[w * 64 + it * 16 + lr] = m;
        }
        __syncthreads();

        if (tid < 64) {
            float mm = lmw[tid];
#pragma unroll
            for (int w2 = 1; w2 < 8; ++w2) mm = fmaxf(mm, lmw[w2 * 64 + tid]);
            mfin[tid] = mm;
        }
        __syncthreads();
    }

    // m for row i = ib + it*16 + lr
    float mreg[4];
#pragma unroll
    for (int it = 0; it < 4; ++it)
        mreg[it] = mfin[it * 16 + lr];

    // ======== PASS 2: flash PV (R16 schedule) + l accumulation from P ========
    f32x4 acc[4][4];
#pragma unroll
    for (int it = 0; it < 4; ++it)
#pragma unroll
        for (int ct = 0; ct < 4; ++ct) {
            f32x4 z = {0.f, 0.f, 0.f, 0.f};
            acc[it][ct] = z;
        }

    float lrun[4] = {0.f, 0.f, 0.f, 0.f};   // per-lane partial sums of P
    f16x8 vA[2][4], vB[2][4];   // half-chunk V buffers (ks 0-1 / ks 2-3), 32 VGPR each

    auto loadVh = [&](int t, int h, f16x8 (&vr)[2][4]) {
        const int tc = (t < 32) ? t : 31;
        const int jb = tc * 128;
#pragma unroll
        for (int ks2 = 0; ks2 < 2; ++ks2)
#pragma unroll
            for (int ct = 0; ct < 4; ++ct)
                vr[ks2][ct] = *reinterpret_cast<const f16x8*>(
                    vb + (size_t)(cw + ct * 16 + lr) * NPOS + jb + (2 * h + ks2) * 32 + 8 * g);
    };
    // E phase (SWAPPED): lane lr holds row i = it*16+lr, cols j = w*16+4g+{0..3}
    // -> one packed f16x4 LDS write per it. live=false for the tail-clamped duplicate
    // call (chunk index 32) so l isn't double-counted.
    auto ephase = [&](const f16x8& k0, const f16x8& k1, char* dst, bool live) {
#pragma unroll
        for (int it = 0; it < 4; ++it) {
            f32x4 e = {0.f, 0.f, 0.f, 0.f};
            e = __builtin_amdgcn_mfma_f32_16x16x32_f16(k0, qf[it][0], e, 0, 0, 0);
            e = __builtin_amdgcn_mfma_f32_16x16x32_f16(k1, qf[it][1], e, 0, 0, 0);
            f16x4 p;
#pragma unroll
            for (int r = 0; r < 4; ++r)
                p[r] = (_Float16)exp2f((e[r] - mreg[it]) * L2E);
            if (live)
                lrun[it] += (float)p[0] + (float)p[1] + (float)p[2] + (float)p[3];
            const int i   = it * 16 + lr;
            const int off = (i * 256 + (w * 32 + 8 * g)) ^ ((i & 15) << 4);
            *reinterpret_cast<f16x4*>(dst + off) = p;
        }
    };
    auto pvhalf = [&](const char* src, int h, const f16x8 (&vr)[2][4]) {
        __builtin_amdgcn_s_setprio(1);
#pragma unroll
        for (int ks2 = 0; ks2 < 2; ++ks2) {
            const int ks = 2 * h + ks2;
            f16x8 pa[4];
#pragma unroll
            for (int it = 0; it < 4; ++it) {
                const int off = (it * 16 + lr) * 256 + ((ks * 64 + g * 16) ^ (lr << 4));
                pa[it] = *reinterpret_cast<const f16x8*>(src + off);
            }
#pragma unroll
            for (int it = 0; it < 4; ++it)
#pragma unroll
                for (int ct = 0; ct < 4; ++ct)
                    acc[it][ct] = __builtin_amdgcn_mfma_f32_16x16x32_f16(pa[it], vr[ks2][ct], acc[it][ct], 0, 0, 0);
        }
        __builtin_amdgcn_s_setprio(0);
    };

    auto region = [&](int t, char* rbuf, char* wbuf, f16x8& ku0, f16x8& ku1,
                      f16x8& kl0, f16x8& kl1) {
        ephase(ku0, ku1, wbuf, (t + 1) < 32);   // P(t+1) using K(t+1)
        loadK(t + 2, kl0, kl1);                 // K(t+2) into the other slot
        pvhalf(rbuf, 0, vA);                    // PV(t) ks 0-1
        loadVh(t + 1, 0, vA);                   // V(t+1) ks 0-1
        pvhalf(rbuf, 1, vB);                    // PV(t) ks 2-3
        loadVh(t + 1, 1, vB);                   // V(t+1) ks 2-3
        LDS_BARRIER();
    };

    // Prologue: P(0) -> pb0, V(0) -> vA/vB, K(1) -> kA.
    loadK(0, kA0, kA1);
    loadVh(0, 0, vA);
    loadVh(0, 1, vB);
    ephase(kA0, kA1, pb0, true);        // P(0) (uses K(0) in kA)
    loadK(1, kA0, kA1);                 // K(1) -> kA (K(0) dead)
    __syncthreads();

#pragma unroll 1
    for (int tp = 0; tp < 16; ++tp) {
        const int t = 2 * tp;
        region(t,     pb0, pb1, kA0, kA1, kB0, kB1);   // chunk t:   P in pb0, K(t+1)=kA
        region(t + 1, pb1, pb0, kB0, kB1, kA0, kA1);   // chunk t+1: P in pb1, K(t+2)=kB
    }
    // (final region's ephase is live=false; all 32 chunks PV'd and l-counted once)

    // ---- reduce l across g and waves ----
#pragma unroll
    for (int it = 0; it < 4; ++it) {
        float s = lrun[it];
#pragma unroll
        for (int mask = 16; mask < 64; mask <<= 1)
            s += __shfl_xor(s, mask, 64);
        if (g == 0)
            lmw[w * 64 + it * 16 + lr] = s;
    }
    __syncthreads();
    if (tid < 64) {
        float ss = 0.f;
#pragma unroll
        for (int w2 = 0; w2 < 8; ++w2) ss += lmw[w2 * 64 + tid];
        lfin[tid] = ss;
    }
    __syncthreads();

    // ---- epilogue: out = gamma * acc / l + x (l from LDS) ----
    const float gm = gamma[0];
#pragma unroll
    for (int it = 0; it < 4; ++it) {
        const int rb = it * 16 + 4 * g;     // local row base for this lane's acc
        const int idx = ib + rb;
        float inv[4];
#pragma unroll
        for (int r = 0; r < 4; ++r)
            inv[r] = 1.0f / lfin[rb + r];
#pragma unroll
        for (int ct = 0; ct < 4; ++ct) {
            const int c = cw + ct * 16 + lr;
            const size_t base = (size_t)(b * CDIM + c) * NPOS + idx;
            const float4 xv = *reinterpret_cast<const float4*>(x + base);
            float4 ov;
            ov.x = gm * (acc[it][ct][0] * inv[0]) + xv.x;
            ov.y = gm * (acc[it][ct][1] * inv[1]) + xv.y;
            ov.z = gm * (acc[it][ct][2] * inv[2]) + xv.z;
            ov.w = gm * (acc[it][ct][3] * inv[3]) + xv.w;
            *reinterpret_cast<float4*>(out + base) = ov;
        }
    }
}

extern "C" void kernel_launch(void* const* d_in, const int* in_sizes, int n_in,
                              void* d_out, int out_size, void* d_ws, size_t ws_size,
                              hipStream_t stream)
{
    (void)in_sizes; (void)n_in; (void)out_size; (void)ws_size;

    const float* x     = (const float*)d_in[0];
    const float* wq    = (const float*)d_in[1];
    const float* bq    = (const float*)d_in[2];
    const float* wk    = (const float*)d_in[3];
    const float* bk    = (const float*)d_in[4];
    const float* wv    = (const float*)d_in[5];
    const float* bv    = (const float*)d_in[6];
    const float* gamma = (const float*)d_in[7];
    float* out = (float*)d_out;

    char* ws = (char*)d_ws;
    const size_t qkBytes = (size_t)NBATCH * NPOS * CQK * sizeof(_Float16);     //  2 MiB each
    const size_t vBytes  = (size_t)NBATCH * CDIM * NPOS * sizeof(_Float16);    // 16 MiB
    const size_t xtBytes = (size_t)NBATCH * NPOS * CDIM * sizeof(_Float16);    // 16 MiB

    _Float16* Qp = (_Float16*)(ws);
    _Float16* Kp = (_Float16*)(ws + qkBytes);
    _Float16* Vp = (_Float16*)(ws + 2 * qkBytes);
    _Float16* Xt = (_Float16*)(ws + 2 * qkBytes + vBytes);
    _Float16* Wh = (_Float16*)(ws + 2 * qkBytes + vBytes + xtBytes);
    float* biasc = (float*)(ws + 2 * qkBytes + vBytes + xtBytes
                              + (size_t)640 * CDIM * sizeof(_Float16));
    // total ws use ~= 36.6 MiB

    w_cvt_kernel<<<dim3(640 * CDIM / 4 / 256), 256, 0, stream>>>(wq, bq, wk, bk, wv, bv, Wh, biasc);
    x_cvt_kernel<<<dim3(NPOS / 64, CDIM / 64, NBATCH), 256, 0, stream>>>(x, Xt);
    proj_gemm_kernel<<<dim3(NPOS / 128, 5, NBATCH), 256, 0, stream>>>(Wh, biasc, Xt, Qp, Kp, Vp);
    attn_fused_kernel<<<dim3(NPOS / 64 * NBATCH), 512, 0, stream>>>(x, Qp, Kp, Vp, gamma, out);
}

// Round 20
// 193.252 us; speedup vs baseline: 1.1767x; 1.0248x over previous
//
#include <hip/hip_runtime.h>
#include <hip/hip_fp16.h>

#define NPOS   4096
#define CDIM   512
#define CQK    64
#define NBATCH 4
#define L2E 1.44269504088896f

typedef _Float16 f16x8 __attribute__((ext_vector_type(8)));
typedef _Float16 f16x4 __attribute__((ext_vector_type(4)));
typedef float    f32x4 __attribute__((ext_vector_type(4)));

// LDS-only drain barrier: keeps global-load (vmcnt) prefetches in flight across
// the barrier (T4). All cross-wave traffic here is LDS, so lgkmcnt(0) suffices.
#define LDS_BARRIER() asm volatile("s_waitcnt lgkmcnt(0)\ns_barrier" ::: "memory")

// ---------------- x convert+transpose (+ fused weight convert) ----------------
// x[b,c,n] f32 -> Xt[b,n,c] f16 via padded LDS tile. Blocks with (z==0 && y==0)
// additionally convert concat[wq;wk;wv] -> Wh f16 and biases -> biasc, with the
// exact same rounding as the old standalone w_cvt kernel -> bitwise-identical
// Wh/biasc -> bitwise-identical Q/K/V downstream. Saves one kernel launch.
__global__ __launch_bounds__(256) void x_cvt_kernel(
    const float* __restrict__ x, _Float16* __restrict__ Xt,
    const float* __restrict__ wq, const float* __restrict__ bq,
    const float* __restrict__ wk, const float* __restrict__ bk,
    const float* __restrict__ wv, const float* __restrict__ bv,
    _Float16* __restrict__ Wh, float* __restrict__ biasc)
{
    __shared__ _Float16 tile[64][66];
    const int b  = blockIdx.z;
    const int c0 = blockIdx.y * 64;
    const int n0 = blockIdx.x * 64;
    const int tid = threadIdx.x;

    // ---- fused W convert: 64 blocks x 256 threads cover 640*512 floats in 5 chunks ----
    if (blockIdx.z == 0 && blockIdx.y == 0) {
        const int gid = blockIdx.x * 256 + tid;          // 0..16383
#pragma unroll 1
        for (int idx4 = gid; idx4 < 640 * CDIM / 4; idx4 += 64 * 256) {
            const int idx = idx4 * 4;
            const float* src;
            if (idx < 64 * 512)       src = wq + idx;
            else if (idx < 128 * 512) src = wk + (idx - 64 * 512);
            else                      src = wv + (idx - 128 * 512);
            const float4 v = *reinterpret_cast<const float4*>(src);
            f16x4 h;
            h[0] = (_Float16)v.x; h[1] = (_Float16)v.y;
            h[2] = (_Float16)v.z; h[3] = (_Float16)v.w;
            *reinterpret_cast<f16x4*>(Wh + idx) = h;
        }
        if (gid < 640) {
            float bb;
            if (gid < 64)       bb = bq[gid];
            else if (gid < 128) bb = bk[gid - 64];
            else                bb = bv[gid - 128];
            biasc[gid] = bb;
        }
    }

    const int rr = tid >> 4;
    const int n4 = (tid & 15) * 4;
#pragma unroll
    for (int i = 0; i < 4; ++i) {
        const int c = i * 16 + rr;
        const float4 v = *reinterpret_cast<const float4*>(
            x + (size_t)(b * CDIM + c0 + c) * NPOS + n0 + n4);
        tile[c][n4 + 0] = (_Float16)v.x;
        tile[c][n4 + 1] = (_Float16)v.y;
        tile[c][n4 + 2] = (_Float16)v.z;
        tile[c][n4 + 3] = (_Float16)v.w;
    }
    __syncthreads();

    const int col = tid & 63;
    const int r4  = tid >> 6;
#pragma unroll
    for (int i = 0; i < 16; ++i) {
        const int n = i * 4 + r4;
        Xt[((size_t)b * NPOS + n0 + n) * CDIM + c0 + col] = tile[col][n];
    }
}

// ---------------- fused QKV projection GEMM: 128x128 tile, LDS double-buffered ----------------
// (R13 structure — measured best; unchanged.)
__global__ __launch_bounds__(256) void proj_gemm_kernel(
    const _Float16* __restrict__ Wh, const float* __restrict__ biasc,
    const _Float16* __restrict__ Xt,
    _Float16* __restrict__ Qp, _Float16* __restrict__ Kp, _Float16* __restrict__ Vp)
{
    __shared__ __align__(16) _Float16 As[2][128 * 32];
    __shared__ __align__(16) _Float16 Bs[2][128 * 32];

    const int tid  = threadIdx.x;
    const int lane = tid & 63;
    const int w    = tid >> 6;       // 0..3
    const int wr   = w >> 1;         // m-half
    const int wc   = w & 1;          // n-half
    const int g    = lane >> 4;
    const int lr   = lane & 15;

    const int b  = blockIdx.z;
    const int m0 = blockIdx.y * 128;
    const int n0 = blockIdx.x * 128;

    const _Float16* xb = Xt + (size_t)b * NPOS * CDIM;

    const int srow = tid >> 2;
    const int schk = (tid & 3) * 8;

    f16x8 sA[2], sB[2];
    auto gload = [&](int kk) {
#pragma unroll
        for (int rnd = 0; rnd < 2; ++rnd) {
            const int row = srow + rnd * 64;
            sA[rnd] = *reinterpret_cast<const f16x8*>(
                Wh + (size_t)(m0 + row) * CDIM + kk + schk);
            sB[rnd] = *reinterpret_cast<const f16x8*>(
                xb + (size_t)(n0 + row) * CDIM + kk + schk);
        }
    };
    auto dswrite = [&](int buf) {
#pragma unroll
        for (int rnd = 0; rnd < 2; ++rnd) {
            const int row = srow + rnd * 64;
            *reinterpret_cast<f16x8*>(&As[buf][row * 32 + schk]) = sA[rnd];
            *reinterpret_cast<f16x8*>(&Bs[buf][row * 32 + schk]) = sB[rnd];
        }
    };

    f32x4 acc[4][4];
#pragma unroll
    for (int it = 0; it < 4; ++it)
#pragma unroll
        for (int ct = 0; ct < 4; ++ct) {
            f32x4 z = {0.f, 0.f, 0.f, 0.f};
            acc[it][ct] = z;
        }

    auto compute = [&](int buf) {
        f16x8 a[4], bf[4];
#pragma unroll
        for (int it = 0; it < 4; ++it)
            a[it] = *reinterpret_cast<const f16x8*>(
                &As[buf][(wr * 64 + it * 16 + lr) * 32 + 8 * g]);
#pragma unroll
        for (int ct = 0; ct < 4; ++ct)
            bf[ct] = *reinterpret_cast<const f16x8*>(
                &Bs[buf][(wc * 64 + ct * 16 + lr) * 32 + 8 * g]);
#pragma unroll
        for (int it = 0; it < 4; ++it)
#pragma unroll
            for (int ct = 0; ct < 4; ++ct)
                acc[it][ct] = __builtin_amdgcn_mfma_f32_16x16x32_f16(a[it], bf[ct], acc[it][ct], 0, 0, 0);
    };

    gload(0);
    dswrite(0);
    __syncthreads();

#pragma unroll 1
    for (int t = 0; t < 16; ++t) {
        if (t < 15) gload((t + 1) * 32);
        compute(t & 1);
        if (t < 15) dswrite((t + 1) & 1);
        __syncthreads();
    }

    if (m0 == 0) {
        _Float16* dst = (wr == 0) ? Qp : Kp;
#pragma unroll
        for (int it = 0; it < 4; ++it) {
            const int gmb = m0 + wr * 64 + it * 16 + 4 * g;
            const int ob  = gmb & 63;
#pragma unroll
            for (int ct = 0; ct < 4; ++ct) {
                const int n = n0 + wc * 64 + ct * 16 + lr;
                f16x4 h;
#pragma unroll
                for (int r = 0; r < 4; ++r)
                    h[r] = (_Float16)(acc[it][ct][r] + biasc[gmb + r]);
                *reinterpret_cast<f16x4*>(dst + ((size_t)b * NPOS + n) * CQK + ob) = h;
            }
        }
    } else {
#pragma unroll
        for (int it = 0; it < 4; ++it) {
            const int gmb = m0 + wr * 64 + it * 16 + 4 * g;
#pragma unroll
            for (int ct = 0; ct < 4; ++ct) {
                const int n = n0 + wc * 64 + ct * 16 + lr;
#pragma unroll
                for (int r = 0; r < 4; ++r) {
                    const int c = gmb + r - 128;
                    Vp[((size_t)b * CDIM + c) * NPOS + n] =
                        (_Float16)(acc[it][ct][r] + biasc[gmb + r]);
                }
            }
        }
    }
}

// ---------------- Fused attention: pass 1 (row MAX only) + pass 2 (flash PV + l-from-P) ----------------
// (R18/R19 structure — best measured; unchanged this round.)
__global__ __launch_bounds__(512, 2) void attn_fused_kernel(
    const float* __restrict__ x, const _Float16* __restrict__ Qp, const _Float16* __restrict__ Kp,
    const _Float16* __restrict__ Vp, const float* __restrict__ gamma, float* __restrict__ out)
{
    __shared__ __align__(16) _Float16 Pl[2][64 * 128];
    __shared__ float lmw[8 * 64];
    __shared__ float mfin[64];
    __shared__ float lfin[64];
    char* pb0 = (char*)Pl[0];
    char* pb1 = (char*)Pl[1];

    const int tid  = threadIdx.x;
    const int lane = tid & 63;
    const int w    = tid >> 6;      // 0..7
    const int g    = lane >> 4;     // 0..3
    const int lr   = lane & 15;

    // XCD-aware decode: batch b -> XCDs {2b,2b+1} so each XCD L2 holds one batch's V+K.
    const int bid = blockIdx.x;
    const int b   = (bid & 7) >> 1;
    const int ib  = (((bid >> 3) << 1) | (bid & 1)) * 64;
    const int cw  = w * 64;

    const _Float16* kb = Kp + (size_t)b * NPOS * CQK;
    const _Float16* vb = Vp + (size_t)b * CDIM * NPOS;

    f16x8 qf[4][2];
#pragma unroll
    for (int it = 0; it < 4; ++it)
#pragma unroll
        for (int ks = 0; ks < 2; ++ks)
            qf[it][ks] = *reinterpret_cast<const f16x8*>(
                Qp + (b * NPOS + ib + it * 16 + lr) * CQK + ks * 32 + 8 * g);

    f16x8 kA0, kA1, kB0, kB1;   // 2-slot K prefetch (pass 2)
    auto loadK = [&](int t, f16x8& k0, f16x8& k1) {
        const int tc = (t < 32) ? t : 31;
        const int j = tc * 128 + w * 16 + lr;
        k0 = *reinterpret_cast<const f16x8*>(kb + j * CQK + 8 * g);
        k1 = *reinterpret_cast<const f16x8*>(kb + j * CQK + 32 + 8 * g);
    };

    // ======== PASS 1: row max only (cheap VALU: 4 fmax-trees per chunk) ========
    {
        float mrun[4];
#pragma unroll
        for (int it = 0; it < 4; ++it) mrun[it] = -1e30f;

        auto step = [&](const f16x8& k0, const f16x8& k1) {
#pragma unroll
            for (int it = 0; it < 4; ++it) {
                f32x4 e = {0.f, 0.f, 0.f, 0.f};
                e = __builtin_amdgcn_mfma_f32_16x16x32_f16(k0, qf[it][0], e, 0, 0, 0);
                e = __builtin_amdgcn_mfma_f32_16x16x32_f16(k1, qf[it][1], e, 0, 0, 0);
                mrun[it] = fmaxf(mrun[it],
                                 fmaxf(fmaxf(e[0], e[1]), fmaxf(e[2], e[3])));
            }
        };

        loadK(0, kA0, kA1);
#pragma unroll 1
        for (int tp = 0; tp < 16; ++tp) {
            const int t = 2 * tp;
            loadK(t + 1, kB0, kB1);
            step(kA0, kA1);
            loadK(t + 2, kA0, kA1);
            step(kB0, kB1);
        }

        // reduce across g (lanes lr, lr+16, lr+32, lr+48), then across waves via LDS
#pragma unroll
        for (int it = 0; it < 4; ++it) {
            float m = mrun[it];
#pragma unroll
            for (int mask = 16; mask < 64; mask <<= 1)
                m = fmaxf(m, __shfl_xor(m, mask, 64));
            if (g == 0)
                lmw[w * 64 + it * 16 + lr] = m;
        }
        __syncthreads();

        if (tid < 64) {
            float mm = lmw[tid];
#pragma unroll
            for (int w2 = 1; w2 < 8; ++w2) mm = fmaxf(mm, lmw[w2 * 64 + tid]);
            mfin[tid] = mm;
        }
        __syncthreads();
    }

    // m for row i = ib + it*16 + lr
    float mreg[4];
#pragma unroll
    for (int it = 0; it < 4; ++it)
        mreg[it] = mfin[it * 16 + lr];

    // ======== PASS 2: flash PV (R16 schedule) + l accumulation from P ========
    f32x4 acc[4][4];
#pragma unroll
    for (int it = 0; it < 4; ++it)
#pragma unroll
        for (int ct = 0; ct < 4; ++ct) {
            f32x4 z = {0.f, 0.f, 0.f, 0.f};
            acc[it][ct] = z;
        }

    float lrun[4] = {0.f, 0.f, 0.f, 0.f};   // per-lane partial sums of P
    f16x8 vA[2][4], vB[2][4];   // half-chunk V buffers (ks 0-1 / ks 2-3), 32 VGPR each

    auto loadVh = [&](int t, int h, f16x8 (&vr)[2][4]) {
        const int tc = (t < 32) ? t : 31;
        const int jb = tc * 128;
#pragma unroll
        for (int ks2 = 0; ks2 < 2; ++ks2)
#pragma unroll
            for (int ct = 0; ct < 4; ++ct)
                vr[ks2][ct] = *reinterpret_cast<const f16x8*>(
                    vb + (size_t)(cw + ct * 16 + lr) * NPOS + jb + (2 * h + ks2) * 32 + 8 * g);
    };
    // E phase (SWAPPED): lane lr holds row i = it*16+lr, cols j = w*16+4g+{0..3}
    // -> one packed f16x4 LDS write per it. live=false for the tail-clamped duplicate
    // call (chunk index 32) so l isn't double-counted.
    auto ephase = [&](const f16x8& k0, const f16x8& k1, char* dst, bool live) {
#pragma unroll
        for (int it = 0; it < 4; ++it) {
            f32x4 e = {0.f, 0.f, 0.f, 0.f};
            e = __builtin_amdgcn_mfma_f32_16x16x32_f16(k0, qf[it][0], e, 0, 0, 0);
            e = __builtin_amdgcn_mfma_f32_16x16x32_f16(k1, qf[it][1], e, 0, 0, 0);
            f16x4 p;
#pragma unroll
            for (int r = 0; r < 4; ++r)
                p[r] = (_Float16)exp2f((e[r] - mreg[it]) * L2E);
            if (live)
                lrun[it] += (float)p[0] + (float)p[1] + (float)p[2] + (float)p[3];
            const int i   = it * 16 + lr;
            const int off = (i * 256 + (w * 32 + 8 * g)) ^ ((i & 15) << 4);
            *reinterpret_cast<f16x4*>(dst + off) = p;
        }
    };
    auto pvhalf = [&](const char* src, int h, const f16x8 (&vr)[2][4]) {
        __builtin_amdgcn_s_setprio(1);
#pragma unroll
        for (int ks2 = 0; ks2 < 2; ++ks2) {
            const int ks = 2 * h + ks2;
            f16x8 pa[4];
#pragma unroll
            for (int it = 0; it < 4; ++it) {
                const int off = (it * 16 + lr) * 256 + ((ks * 64 + g * 16) ^ (lr << 4));
                pa[it] = *reinterpret_cast<const f16x8*>(src + off);
            }
#pragma unroll
            for (int it = 0; it < 4; ++it)
#pragma unroll
                for (int ct = 0; ct < 4; ++ct)
                    acc[it][ct] = __builtin_amdgcn_mfma_f32_16x16x32_f16(pa[it], vr[ks2][ct], acc[it][ct], 0, 0, 0);
        }
        __builtin_amdgcn_s_setprio(0);
    };

    auto region = [&](int t, char* rbuf, char* wbuf, f16x8& ku0, f16x8& ku1,
                      f16x8& kl0, f16x8& kl1) {
        ephase(ku0, ku1, wbuf, (t + 1) < 32);   // P(t+1) using K(t+1)
        loadK(t + 2, kl0, kl1);                 // K(t+2) into the other slot
        pvhalf(rbuf, 0, vA);                    // PV(t) ks 0-1
        loadVh(t + 1, 0, vA);                   // V(t+1) ks 0-1
        pvhalf(rbuf, 1, vB);                    // PV(t) ks 2-3
        loadVh(t + 1, 1, vB);                   // V(t+1) ks 2-3
        LDS_BARRIER();
    };

    // Prologue: P(0) -> pb0, V(0) -> vA/vB, K(1) -> kA.
    loadK(0, kA0, kA1);
    loadVh(0, 0, vA);
    loadVh(0, 1, vB);
    ephase(kA0, kA1, pb0, true);        // P(0) (uses K(0) in kA)
    loadK(1, kA0, kA1);                 // K(1) -> kA (K(0) dead)
    __syncthreads();

#pragma unroll 1
    for (int tp = 0; tp < 16; ++tp) {
        const int t = 2 * tp;
        region(t,     pb0, pb1, kA0, kA1, kB0, kB1);   // chunk t:   P in pb0, K(t+1)=kA
        region(t + 1, pb1, pb0, kB0, kB1, kA0, kA1);   // chunk t+1: P in pb1, K(t+2)=kB
    }
    // (final region's ephase is live=false; all 32 chunks PV'd and l-counted once)

    // ---- reduce l across g and waves ----
#pragma unroll
    for (int it = 0; it < 4; ++it) {
        float s = lrun[it];
#pragma unroll
        for (int mask = 16; mask < 64; mask <<= 1)
            s += __shfl_xor(s, mask, 64);
        if (g == 0)
            lmw[w * 64 + it * 16 + lr] = s;
    }
    __syncthreads();
    if (tid < 64) {
        float ss = 0.f;
#pragma unroll
        for (int w2 = 0; w2 < 8; ++w2) ss += lmw[w2 * 64 + tid];
        lfin[tid] = ss;
    }
    __syncthreads();

    // ---- epilogue: out = gamma * acc / l + x (l from LDS) ----
    const float gm = gamma[0];
#pragma unroll
    for (int it = 0; it < 4; ++it) {
        const int rb = it * 16 + 4 * g;     // local row base for this lane's acc
        const int idx = ib + rb;
        float inv[4];
#pragma unroll
        for (int r = 0; r < 4; ++r)
            inv[r] = 1.0f / lfin[rb + r];
#pragma unroll
        for (int ct = 0; ct < 4; ++ct) {
            const int c = cw + ct * 16 + lr;
            const size_t base = (size_t)(b * CDIM + c) * NPOS + idx;
            const float4 xv = *reinterpret_cast<const float4*>(x + base);
            float4 ov;
            ov.x = gm * (acc[it][ct][0] * inv[0]) + xv.x;
            ov.y = gm * (acc[it][ct][1] * inv[1]) + xv.y;
            ov.z = gm * (acc[it][ct][2] * inv[2]) + xv.z;
            ov.w = gm * (acc[it][ct][3] * inv[3]) + xv.w;
            *reinterpret_cast<float4*>(out + base) = ov;
        }
    }
}

extern "C" void kernel_launch(void* const* d_in, const int* in_sizes, int n_in,
                              void* d_out, int out_size, void* d_ws, size_t ws_size,
                              hipStream_t stream)
{
    (void)in_sizes; (void)n_in; (void)out_size; (void)ws_size;

    const float* x     = (const float*)d_in[0];
    const float* wq    = (const float*)d_in[1];
    const float* bq    = (const float*)d_in[2];
    const float* wk    = (const float*)d_in[3];
    const float* bk    = (const float*)d_in[4];
    const float* wv    = (const float*)d_in[5];
    const float* bv    = (const float*)d_in[6];
    const float* gamma = (const float*)d_in[7];
    float* out = (float*)d_out;

    char* ws = (char*)d_ws;
    const size_t qkBytes = (size_t)NBATCH * NPOS * CQK * sizeof(_Float16);     //  2 MiB each
    const size_t vBytes  = (size_t)NBATCH * CDIM * NPOS * sizeof(_Float16);    // 16 MiB
    const size_t xtBytes = (size_t)NBATCH * NPOS * CDIM * sizeof(_Float16);    // 16 MiB

    _Float16* Qp = (_Float16*)(ws);
    _Float16* Kp = (_Float16*)(ws + qkBytes);
    _Float16* Vp = (_Float16*)(ws + 2 * qkBytes);
    _Float16* Xt = (_Float16*)(ws + 2 * qkBytes + vBytes);
    _Float16* Wh = (_Float16*)(ws + 2 * qkBytes + vBytes + xtBytes);
    float* biasc = (float*)(ws + 2 * qkBytes + vBytes + xtBytes
                              + (size_t)640 * CDIM * sizeof(_Float16));
    // total ws use ~= 36.6 MiB

    x_cvt_kernel<<<dim3(NPOS / 64, CDIM / 64, NBATCH), 256, 0, stream>>>(
        x, Xt, wq, bq, wk, bk, wv, bv, Wh, biasc);
    proj_gemm_kernel<<<dim3(NPOS / 128, 5, NBATCH), 256, 0, stream>>>(Wh, biasc, Xt, Qp, Kp, Vp);
    attn_fused_kernel<<<dim3(NPOS / 64 * NBATCH), 512, 0, stream>>>(x, Qp, Kp, Vp, gamma, out);
}